// Round 4
// baseline (2165.723 us; speedup 1.0000x reference)
//
#include <hip/hip_runtime.h>

// ---------------------------------------------------------------------------
// PoseVQVAE fused forward. Dual-mode (f32/bf16 storage sniffed on-device).
// Math core: f16 MFMA, 2-plane split (residual plane pre-scaled by 2^12):
//   encoder fc1..mu + VQ: 3 passes (A0B0 main; A1B0+A0B1 folded via tmp*2^-12)
//   decoder fc4..out: 1-plane f16 (tolerance-bound).
// All global access coalesced; embed pre-transposed to eT[1024][64] f32.
// ---------------------------------------------------------------------------

using half8 = __attribute__((ext_vector_type(8))) _Float16;
using f32x4 = __attribute__((ext_vector_type(4))) float;

#define USHORT unsigned short
#define UINT   unsigned int

// plane sizes (elements)
#define PS_W1  139264   // 544*256
#define PS_W2  65536    // 256*256
#define PS_MU  16384    // 256*64
#define PS_WE  65536    // 64*1024

// ---- ws layout (bytes), 64B-aligned ----
static const size_t OFF_IDX    = 0;          // 65536*4
static const size_t OFF_COUNTS = 262144;     // 1024*4
static const size_t OFF_LOSS   = 266240;     // 4 (+pad)
static const size_t OFF_ENORM  = 266304;     // 1024*4
static const size_t OFF_ET     = 270400;     // 1024*64*4 = 262144
static const size_t OFF_W1     = 532544;     // 2*139264*2 = 557056
static const size_t OFF_W2     = 1089600;    // 2*65536*2  = 262144
static const size_t OFF_W3     = 1351744;    // 262144
static const size_t OFF_WMU    = 1613888;    // 2*16384*2  = 65536
static const size_t OFF_WE     = 1679424;    // 262144
static const size_t OFF_W4     = 1941568;    // 352*256*2  = 180224
static const size_t OFF_W5     = 2121792;    // 131072
static const size_t OFF_W6     = 2252864;    // 131072
static const size_t OFF_WO     = 2383936;    // 256*272*2  = 139264 -> 2.52MB

#define RS (1.0f/4096.0f)

__device__ __forceinline__ float b2f(USHORT u){
  return __uint_as_float(((UINT)u) << 16);
}
__device__ __forceinline__ USHORT f2b(float f){            // RNE f32->bf16
  UINT u = __float_as_uint(f);
  u += 0x7fffu + ((u >> 16) & 1u);
  return (USHORT)(u >> 16);
}
__device__ __forceinline__ USHORT h2u(_Float16 h){ return __builtin_bit_cast(USHORT, h); }
__device__ __forceinline__ _Float16 u2h(USHORT u){ return __builtin_bit_cast(_Float16, u); }
__device__ __forceinline__ float loadF(const void* p, long i, int f32m){
  if (f32m) return ((const float*)p)[i];
  return b2f(((const USHORT*)p)[i]);
}
// 2-plane f16 split; residual plane scaled by 2^12 (exact) to dodge denorms
__device__ __forceinline__ void split2s(float v, USHORT& a, USHORT& b){
  _Float16 t0 = (_Float16)v;
  float r = (v - (float)t0) * 4096.f;
  a = h2u(t0); b = h2u((_Float16)r);
}
__device__ __forceinline__ f32x4 mfmah(half8 a, half8 b, f32x4 c){
  return __builtin_amdgcn_mfma_f32_16x16x32_f16(a, b, c, 0, 0, 0);
}
__device__ __forceinline__ half8 ld8(const USHORT* p){ return *(const half8*)p; }

__device__ __forceinline__ int detect_f32(const void* x){
  UINT u = ((const UINT*)x)[threadIdx.x & 63];
  int e = (int)((u >> 7) & 0xFFu);
  unsigned long long m = __ballot(e >= 117 && e <= 130);
  return __popcll(m) < 32;
}

// ---------------------------------------------------------------------------
// prep: repack weights into [K/8][N][8] f16 planes; eT transpose; enorm; zeros
// ---------------------------------------------------------------------------
__device__ __forceinline__ void fillW(USHORT* dst, const void* src,
                                      int Kpad, int N, int Ksrc, int Nsrc,
                                      int srcStride, bool kmajor, int t,
                                      int f32m, int planes)
{
  int total = Kpad * N;
  if (t >= total) return;
  int j = t & 7, rest = t >> 3;
  int n = rest % N, kg = rest / N;
  int k = kg*8 + j;
  float v = 0.f;
  if (k < Ksrc && n < Nsrc)
    v = loadF(src, kmajor ? (long)k*srcStride + n : (long)n*srcStride + k, f32m);
  if (planes == 1){ dst[t] = h2u((_Float16)v); return; }
  USHORT t0, t1; split2s(v, t0, t1);
  dst[t] = t0; dst[total + t] = t1;
}

__global__ void vq_prep_kernel(
    const void* xx,
    const void* fc1w, const void* fc2w, const void* fc3w,
    const void* muw,  const void* fc4w, const void* fc5w,
    const void* fc6w, const void* outw, const void* embed,
    USHORT* W1p, USHORT* W2p, USHORT* W3p, USHORT* Wmup, USHORT* Wep,
    USHORT* W4p, USHORT* W5p, USHORT* W6p, USHORT* Wop,
    float* eT, float* enorm, UINT* counts, float* loss_sum)
{
  int f32m = detect_f32(xx);
  int t = blockIdx.x * 256 + threadIdx.x;
  switch (blockIdx.y){
    case 0: fillW(W1p,  fc1w, 544, 256, 534, 256, 534, false, t, f32m, 2); break;
    case 1: fillW(W2p,  fc2w, 256, 256, 256, 256, 256, false, t, f32m, 2); break;
    case 2: fillW(W3p,  fc3w, 256, 256, 256, 256, 256, false, t, f32m, 2); break;
    case 3: fillW(Wmup, muw,  256,  64, 256,  64, 256, false, t, f32m, 2); break;
    case 4: fillW(Wep,  embed, 64, 1024, 64, 1024, 1024, true, t, f32m, 2); break;
    case 5: fillW(W4p,  fc4w, 352, 256, 331, 256, 331, false, t, f32m, 1); break;
    case 6: fillW(W5p,  fc5w, 256, 256, 256, 256, 256, false, t, f32m, 1); break;
    case 7: fillW(W6p,  fc6w, 256, 256, 256, 256, 256, false, t, f32m, 1); break;
    case 8: fillW(Wop,  outw, 256, 272, 256, 267, 256, false, t, f32m, 1); break;
    case 9:
      if (t < 1024){
        double s = 0.0;
        for (int l = 0; l < 64; ++l){
          double e = (double)loadF(embed, (long)l*1024 + t, f32m); s += e*e;
        }
        enorm[t] = (float)s;
      }
      break;
    case 10:
      if (t < 1024) counts[t] = 0u;
      if (t == 1024) *loss_sum = 0.f;
      break;
    case 11:   // eT[code][l] = embed[l][code]; coalesced read, scattered write
      if (t < 65536){
        int l = t >> 10, code = t & 1023;
        eT[(long)code*64 + l] = loadF(embed, t, f32m);
      }
      break;
  }
}

// ---------------------------------------------------------------------------
// encoder: 32 rows/block, 128 threads (2 waves × 16 rows, wave-private LDS).
// LDS union (37888 B): staging sS [2 planes][32][296] for fc1 K-halves;
// activations sP0/sP1 [32][264] alias after fc1.
// ---------------------------------------------------------------------------
__global__ __launch_bounds__(128, 2) void vq_enc_kernel(
    const void* __restrict__ x,  const void* __restrict__ cc,
    const void* __restrict__ b1, const void* __restrict__ b2,
    const void* __restrict__ b3, const void* __restrict__ bmu,
    const USHORT* __restrict__ W1p, const USHORT* __restrict__ W2p,
    const USHORT* __restrict__ W3p, const USHORT* __restrict__ Wmup,
    const USHORT* __restrict__ Wep, const float* __restrict__ eT,
    const float* __restrict__ enorm,
    int* __restrict__ idxws, UINT* __restrict__ counts,
    float* __restrict__ loss_sum)
{
  __shared__ __align__(16) USHORT sS[2*32*296];   // 18944 ushorts
  USHORT* sP0 = sS;                                // [32][264]
  USHORT* sP1 = sS + 8448;

  const int f32m = detect_f32(x);
  const int tid  = threadIdx.x;
  const int w    = tid >> 6;
  const int lane = tid & 63;
  const int quad = lane >> 4;
  const int l16  = lane & 15;
  const int row  = w*16 + l16;
  const long gbase = (long)blockIdx.x * 32;
  const f32x4 z4 = {0.f, 0.f, 0.f, 0.f};

  f32x4 acc[16];
  #pragma unroll
  for (int i = 0; i < 16; ++i) acc[i] = z4;

  // ---- fc1: K=544 in two staged halves (cols [0,288) 9 kc, [288,544) 8 kc)
  for (int half = 0; half < 2; ++half){
    const int kb = half ? 288 : 0;
    const int wd = half ? 256 : 288;
    const int nkc = half ? 8 : 9;
    // stage this wave's 16 rows, coalesced
    for (int rr = 0; rr < 16; ++rr){
      int lr = w*16 + rr;
      long grow = gbase + lr;
      for (int col = lane; col < wd; col += 64){
        int gc = kb + col;
        float v = 0.f;
        if (gc < 267)      v = loadF(x,  grow*267 + gc, f32m);
        else if (gc < 534) v = loadF(cc, grow*267 + (gc - 267), f32m);
        USHORT t0, t1; split2s(v, t0, t1);
        sS[lr*296 + col] = t0;
        sS[32*296 + lr*296 + col] = t1;
      }
    }
    __syncthreads();
    for (int kc = 0; kc < nkc; ++kc){
      int koff = kc*32 + quad*8;
      half8 A0 = ld8(&sS[row*296 + koff]);
      half8 A1 = ld8(&sS[32*296 + row*296 + koff]);
      const USHORT* base = W1p + (((kb>>3) + kc*4 + quad)*256 + l16)*8;
      #pragma unroll
      for (int cb = 0; cb < 16; ++cb){
        half8 B0 = ld8(base + cb*128);
        acc[cb] = mfmah(A0, B0, acc[cb]);
        if (f32m){
          half8 B1 = ld8(base + PS_W1 + cb*128);
          f32x4 t = mfmah(A1, B0, z4);
          t = mfmah(A0, B1, t);
          #pragma unroll
          for (int i = 0; i < 4; ++i) acc[cb][i] += t[i]*RS;
        }
      }
    }
    __syncthreads();
  }

  // epilogue fc1 -> activation planes (aliases staging; barrier above)
  #pragma unroll
  for (int cb = 0; cb < 16; ++cb){
    int col = cb*16 + l16;
    float bias = loadF(b1, col, f32m);
    #pragma unroll
    for (int r = 0; r < 4; ++r){
      int orow = w*16 + quad*4 + r;
      float h = fmaxf(acc[cb][r] + bias, 0.f);
      USHORT t0, t1; split2s(h, t0, t1);
      sP0[orow*264 + col] = t0;
      sP1[orow*264 + col] = t1;
    }
  }

  // ---- fc2, fc3: K=256, in-place (wave-private rows)
  for (int layer = 0; layer < 2; ++layer){
    const USHORT* Wp = layer ? W3p : W2p;
    const void*   bb = layer ? b3  : b2;
    #pragma unroll
    for (int i = 0; i < 16; ++i) acc[i] = z4;
    for (int kc = 0; kc < 8; ++kc){
      int koff = kc*32 + quad*8;
      half8 A0 = ld8(&sP0[row*264 + koff]);
      half8 A1 = ld8(&sP1[row*264 + koff]);
      const USHORT* base = Wp + ((kc*4 + quad)*256 + l16)*8;
      #pragma unroll
      for (int cb = 0; cb < 16; ++cb){
        half8 B0 = ld8(base + cb*128);
        acc[cb] = mfmah(A0, B0, acc[cb]);
        if (f32m){
          half8 B1 = ld8(base + PS_W2 + cb*128);
          f32x4 t = mfmah(A1, B0, z4);
          t = mfmah(A0, B1, t);
          #pragma unroll
          for (int i = 0; i < 4; ++i) acc[cb][i] += t[i]*RS;
        }
      }
    }
    #pragma unroll
    for (int cb = 0; cb < 16; ++cb){
      int col = cb*16 + l16;
      float bias = loadF(bb, col, f32m);
      #pragma unroll
      for (int r = 0; r < 4; ++r){
        int orow = w*16 + quad*4 + r;
        float h = fmaxf(acc[cb][r] + bias, 0.f);
        USHORT t0, t1; split2s(h, t0, t1);
        sP0[orow*264 + col] = t0;
        sP1[orow*264 + col] = t1;
      }
    }
  }

  // ---- mu: N=64
  f32x4 accm[4];
  #pragma unroll
  for (int i = 0; i < 4; ++i) accm[i] = z4;
  for (int kc = 0; kc < 8; ++kc){
    int koff = kc*32 + quad*8;
    half8 A0 = ld8(&sP0[row*264 + koff]);
    half8 A1 = ld8(&sP1[row*264 + koff]);
    const USHORT* base = Wmup + ((kc*4 + quad)*64 + l16)*8;
    #pragma unroll
    for (int cb = 0; cb < 4; ++cb){
      half8 B0 = ld8(base + cb*128);
      accm[cb] = mfmah(A0, B0, accm[cb]);
      if (f32m){
        half8 B1 = ld8(base + PS_MU + cb*128);
        f32x4 t = mfmah(A1, B0, z4);
        t = mfmah(A0, B1, t);
        #pragma unroll
        for (int i = 0; i < 4; ++i) accm[cb][i] += t[i]*RS;
      }
    }
  }
  #pragma unroll
  for (int cb = 0; cb < 4; ++cb){
    int col = cb*16 + l16;
    float bias = loadF(bmu, col, f32m);
    #pragma unroll
    for (int r = 0; r < 4; ++r){
      int orow = w*16 + quad*4 + r;
      float m = accm[cb][r] + bias;
      USHORT t0, t1; split2s(m, t0, t1);
      sP0[orow*264 + col] = t0;
      sP1[orow*264 + col] = t1;
    }
  }

  // ---- VQ: argmin_k ( ||e_k||^2 - 2 mu.e_k )
  half8 M0[2], M1[2];
  #pragma unroll
  for (int kc = 0; kc < 2; ++kc){
    int koff = kc*32 + quad*8;
    M0[kc] = ld8(&sP0[row*264 + koff]);
    M1[kc] = ld8(&sP1[row*264 + koff]);
  }
  float minv[4] = {3.4e38f, 3.4e38f, 3.4e38f, 3.4e38f};
  int   minc[4] = {0,0,0,0};
  for (int it = 0; it < 32; ++it){
    f32x4 ad0 = z4, ad1 = z4;
    #pragma unroll
    for (int kc = 0; kc < 2; ++kc){
      const USHORT* base = Wep + ((kc*4 + quad)*1024 + it*32 + l16)*8;
      half8 B00 = ld8(base);
      half8 B01 = ld8(base + 128);
      ad0 = mfmah(M0[kc], B00, ad0);
      ad1 = mfmah(M0[kc], B01, ad1);
      if (f32m){
        half8 B10 = ld8(base + PS_WE);
        half8 B11 = ld8(base + PS_WE + 128);
        f32x4 t0 = mfmah(M1[kc], B00, z4);
        t0 = mfmah(M0[kc], B10, t0);
        f32x4 t1 = mfmah(M1[kc], B01, z4);
        t1 = mfmah(M0[kc], B11, t1);
        #pragma unroll
        for (int i = 0; i < 4; ++i){ ad0[i] += t0[i]*RS; ad1[i] += t1[i]*RS; }
      } else {
        f32x4 t0 = mfmah(M1[kc], B00, z4);
        f32x4 t1 = mfmah(M1[kc], B01, z4);
        #pragma unroll
        for (int i = 0; i < 4; ++i){ ad0[i] += t0[i]*RS; ad1[i] += t1[i]*RS; }
      }
    }
    int code0 = it*32 + l16, code1 = code0 + 16;
    float en0 = enorm[code0], en1 = enorm[code1];
    #pragma unroll
    for (int r = 0; r < 4; ++r){
      float d0 = en0 - 2.f*ad0[r];
      if (d0 < minv[r]){ minv[r] = d0; minc[r] = code0; }
      float d1 = en1 - 2.f*ad1[r];
      if (d1 < minv[r]){ minv[r] = d1; minc[r] = code1; }
    }
  }
  #pragma unroll
  for (int off = 8; off >= 1; off >>= 1){
    #pragma unroll
    for (int r = 0; r < 4; ++r){
      float ov = __shfl_xor(minv[r], off, 64);
      int   oc = __shfl_xor(minc[r], off, 64);
      if (ov < minv[r] || (ov == minv[r] && oc < minc[r])){ minv[r] = ov; minc[r] = oc; }
    }
  }

  // ---- emit idx, loss partial, histogram (q from eT, coalesced rows)
  float lossp = 0.f;
  #pragma unroll
  for (int r = 0; r < 4; ++r){
    int orow = w*16 + quad*4 + r;
    long grow = gbase + orow;
    int code = minc[r];
    #pragma unroll
    for (int j = 0; j < 4; ++j){
      int l = l16 + j*16;
      float qv = eT[(long)code*64 + l];
      float muf = (float)u2h(sP0[orow*264 + l]) + (float)u2h(sP1[orow*264 + l]) * RS;
      float d = qv - muf;
      lossp += d*d;
    }
    if (l16 == 0){
      idxws[grow] = code;
      atomicAdd(&counts[code], 1u);
    }
  }
  #pragma unroll
  for (int off = 32; off >= 1; off >>= 1) lossp += __shfl_xor(lossp, off, 64);
  if (lane == 0) atomicAdd(loss_sum, lossp);
}

// ---------------------------------------------------------------------------
// decoder: 32 rows/block, 128 threads; 1-plane f16 MFMA; q gathered via eT.
// ---------------------------------------------------------------------------
__global__ __launch_bounds__(128, 2) void vq_dec_kernel(
    const void* __restrict__ x,
    const int* __restrict__ idxws, const void* __restrict__ cc,
    const float* __restrict__ eT,
    const void* __restrict__ b4,  const void* __restrict__ b5,
    const void* __restrict__ b6,  const void* __restrict__ bo,
    const USHORT* __restrict__ W4p, const USHORT* __restrict__ W5p,
    const USHORT* __restrict__ W6p, const USHORT* __restrict__ Wop,
    void* __restrict__ out)
{
  __shared__ __align__(16) USHORT sA[32*360];   // s2 staging / h5
  __shared__ __align__(16) USHORT sB[32*264];   // h4 / h6

  const int f32m = detect_f32(x);
  const int tid  = threadIdx.x;
  const int w    = tid >> 6;
  const int lane = tid & 63;
  const int quad = lane >> 4;
  const int l16  = lane & 15;
  const int row  = w*16 + l16;
  const long gbase = (long)blockIdx.x * 32;
  const f32x4 z4 = {0.f, 0.f, 0.f, 0.f};

  // stage s2 = [q | c | 0pad]; q row from eT (coalesced 256B), c coalesced
  for (int rr = 0; rr < 16; ++rr){
    int lr = w*16 + rr;
    long grow = gbase + lr;
    int code = idxws[grow];
    for (int col = lane; col < 360; col += 64){
      float v = 0.f;
      if (col < 64)       v = eT[(long)code*64 + col];
      else if (col < 331) v = loadF(cc, grow*267 + (col - 64), f32m);
      sA[lr*360 + col] = h2u((_Float16)v);
    }
  }
  __syncthreads();

  f32x4 acc[16];
  // ---- fc4: K=352 : sA -> sB
  #pragma unroll
  for (int i = 0; i < 16; ++i) acc[i] = z4;
  for (int kc = 0; kc < 11; ++kc){
    half8 A = ld8(&sA[row*360 + kc*32 + quad*8]);
    const USHORT* base = W4p + ((kc*4 + quad)*256 + l16)*8;
    #pragma unroll
    for (int cb = 0; cb < 16; ++cb)
      acc[cb] = mfmah(A, ld8(base + cb*128), acc[cb]);
  }
  __syncthreads();
  #pragma unroll
  for (int cb = 0; cb < 16; ++cb){
    int col = cb*16 + l16;
    float bias = loadF(b4, col, f32m);
    #pragma unroll
    for (int r = 0; r < 4; ++r){
      int orow = w*16 + quad*4 + r;
      sB[orow*264 + col] = h2u((_Float16)fmaxf(acc[cb][r] + bias, 0.f));
    }
  }

  // ---- fc5: sB -> sA
  #pragma unroll
  for (int i = 0; i < 16; ++i) acc[i] = z4;
  for (int kc = 0; kc < 8; ++kc){
    half8 A = ld8(&sB[row*264 + kc*32 + quad*8]);
    const USHORT* base = W5p + ((kc*4 + quad)*256 + l16)*8;
    #pragma unroll
    for (int cb = 0; cb < 16; ++cb)
      acc[cb] = mfmah(A, ld8(base + cb*128), acc[cb]);
  }
  #pragma unroll
  for (int cb = 0; cb < 16; ++cb){
    int col = cb*16 + l16;
    float bias = loadF(b5, col, f32m);
    #pragma unroll
    for (int r = 0; r < 4; ++r){
      int orow = w*16 + quad*4 + r;
      sA[orow*360 + col] = h2u((_Float16)fmaxf(acc[cb][r] + bias, 0.f));
    }
  }

  // ---- fc6: sA -> sB
  #pragma unroll
  for (int i = 0; i < 16; ++i) acc[i] = z4;
  for (int kc = 0; kc < 8; ++kc){
    half8 A = ld8(&sA[row*360 + kc*32 + quad*8]);
    const USHORT* base = W6p + ((kc*4 + quad)*256 + l16)*8;
    #pragma unroll
    for (int cb = 0; cb < 16; ++cb)
      acc[cb] = mfmah(A, ld8(base + cb*128), acc[cb]);
  }
  #pragma unroll
  for (int cb = 0; cb < 16; ++cb){
    int col = cb*16 + l16;
    float bias = loadF(b6, col, f32m);
    #pragma unroll
    for (int r = 0; r < 4; ++r){
      int orow = w*16 + quad*4 + r;
      sB[orow*264 + col] = h2u((_Float16)fmaxf(acc[cb][r] + bias, 0.f));
    }
  }

  // ---- out: N=272 (267 real) : sB -> global
  f32x4 acco[17];
  #pragma unroll
  for (int i = 0; i < 17; ++i) acco[i] = z4;
  for (int kc = 0; kc < 8; ++kc){
    half8 A = ld8(&sB[row*264 + kc*32 + quad*8]);
    const USHORT* base = Wop + ((kc*4 + quad)*272 + l16)*8;
    #pragma unroll
    for (int cb = 0; cb < 17; ++cb)
      acco[cb] = mfmah(A, ld8(base + cb*128), acco[cb]);
  }
  #pragma unroll
  for (int cb = 0; cb < 17; ++cb){
    int col = cb*16 + l16;
    if (col < 267){
      float bias = loadF(bo, col, f32m);
      #pragma unroll
      for (int r = 0; r < 4; ++r){
        int orow = w*16 + quad*4 + r;
        long oi = (gbase + orow)*267 + col;
        float val = acco[cb][r] + bias;
        if (f32m) ((float*)out)[oi] = val;
        else      ((USHORT*)out)[oi] = f2b(val);
      }
    }
  }
}

// ---------------------------------------------------------------------------
__global__ void vq_fin_kernel(const void* __restrict__ x,
                              const UINT* __restrict__ counts,
                              const float* __restrict__ loss_sum,
                              void* __restrict__ out)
{
  __shared__ float red[4];
  int f32m = detect_f32(x);
  int tid = threadIdx.x;
  float Hl = 0.f;
  for (int k = tid; k < 1024; k += 256){
    float p = (float)counts[k] * (1.f/65536.f);
    Hl -= p * logf(p + 1e-10f);
  }
  #pragma unroll
  for (int off = 32; off >= 1; off >>= 1) Hl += __shfl_xor(Hl, off, 64);
  if ((tid & 63) == 0) red[tid >> 6] = Hl;
  __syncthreads();
  if (tid == 0){
    float H = red[0] + red[1] + red[2] + red[3];
    float loss = *loss_sum * (1.f/4194304.f);   // /(B*L)
    float ppx  = expf(H);
    size_t base = (size_t)65536*267;
    if (f32m){
      ((float*)out)[base]     = loss;
      ((float*)out)[base + 1] = ppx;
    } else {
      ((USHORT*)out)[base]     = f2b(loss);
      ((USHORT*)out)[base + 1] = f2b(ppx);
    }
  }
}

// ---------------------------------------------------------------------------
extern "C" void kernel_launch(void* const* d_in, const int* in_sizes, int n_in,
                              void* d_out, int out_size, void* d_ws, size_t ws_size,
                              hipStream_t stream)
{
  const void* x    = d_in[0];
  const void* c    = d_in[1];
  const void* fc1w = d_in[2];
  const void* fc1b = d_in[3];
  const void* fc2w = d_in[4];
  const void* fc2b = d_in[5];
  const void* fc3w = d_in[6];
  const void* fc3b = d_in[7];
  const void* muw  = d_in[8];
  const void* mub  = d_in[9];
  const void* fc4w = d_in[10];
  const void* fc4b = d_in[11];
  const void* fc5w = d_in[12];
  const void* fc5b = d_in[13];
  const void* fc6w = d_in[14];
  const void* fc6b = d_in[15];
  const void* outw = d_in[16];
  const void* outb = d_in[17];
  const void* embed= d_in[18];

  char* ws = (char*)d_ws;
  int*    idxws  = (int*)   (ws + OFF_IDX);
  UINT*   counts = (UINT*)  (ws + OFF_COUNTS);
  float*  lsum   = (float*) (ws + OFF_LOSS);
  float*  enorm  = (float*) (ws + OFF_ENORM);
  float*  eT     = (float*) (ws + OFF_ET);
  USHORT* W1p = (USHORT*)(ws + OFF_W1);
  USHORT* W2p = (USHORT*)(ws + OFF_W2);
  USHORT* W3p = (USHORT*)(ws + OFF_W3);
  USHORT* Wmup= (USHORT*)(ws + OFF_WMU);
  USHORT* Wep = (USHORT*)(ws + OFF_WE);
  USHORT* W4p = (USHORT*)(ws + OFF_W4);
  USHORT* W5p = (USHORT*)(ws + OFF_W5);
  USHORT* W6p = (USHORT*)(ws + OFF_W6);
  USHORT* Wop = (USHORT*)(ws + OFF_WO);

  dim3 pgrid(544, 12, 1);
  vq_prep_kernel<<<pgrid, 256, 0, stream>>>(
      x, fc1w, fc2w, fc3w, muw, fc4w, fc5w, fc6w, outw, embed,
      W1p, W2p, W3p, Wmup, Wep, W4p, W5p, W6p, Wop, eT, enorm, counts, lsum);

  vq_enc_kernel<<<2048, 128, 0, stream>>>(
      x, c, fc1b, fc2b, fc3b, mub,
      W1p, W2p, W3p, Wmup, Wep, eT, enorm, idxws, counts, lsum);

  vq_dec_kernel<<<2048, 128, 0, stream>>>(
      x, idxws, c, eT, fc4b, fc5b, fc6b, outb,
      W4p, W5p, W6p, Wop, d_out);

  vq_fin_kernel<<<1, 256, 0, stream>>>(x, counts, lsum, d_out);
}